// Round 3
// baseline (381.066 us; speedup 1.0000x reference)
//
#include <hip/hip_runtime.h>
#include <stdint.h>

#define N_NODES 100000
#define N_EDGES 1600000
#define D 128
#define PAD 48             // padded-CSR row stride (Poisson(16) tail: P(deg>=48)~5e-11/node)
#define NTILES (N_NODES / 16)   // 6250 exact
#define GRID_GEMM 2048
#define GRID_SCAT 2048
#define CAST_BLOCKS (N_NODES * D / 8 / 256)   // 6250 exact

typedef unsigned int uint32;
typedef __attribute__((ext_vector_type(8))) short short8;   // 8 bf16 = 4 VGPRs
typedef __attribute__((ext_vector_type(4))) float f32x4;

__device__ __forceinline__ unsigned short f2bf(float f) {
  unsigned u = __builtin_bit_cast(unsigned, f);
  u += 0x7fffu + ((u >> 16) & 1u);          // round-to-nearest-even
  return (unsigned short)(u >> 16);
}
__device__ __forceinline__ float bflo(unsigned v) {
  return __builtin_bit_cast(float, v << 16);
}
__device__ __forceinline__ float bfhi(unsigned v) {
  return __builtin_bit_cast(float, v & 0xffff0000u);
}

// ---------------- padded-CSR build: one atomic-scatter kernel ----------------
// csrp[dst*PAD + slot] = src, slot = running count. Order within a row is
// arrival order (non-deterministic) -- same property as the previous
// bucket-run build, which passes at absmax 0.03125 (bf16 quantization
// dominates the error, not summation order).
__global__ __launch_bounds__(256) void k_scat(const int* __restrict__ src,
                                              const int* __restrict__ dst,
                                              int* __restrict__ cnt,
                                              int* __restrict__ csrp) {
  for (int e = blockIdx.x * 256 + threadIdx.x; e < N_EDGES; e += GRID_SCAT * 256) {
    int d = dst[e];
    int s = src[e];
    int slot = atomicAdd(&cnt[d], 1);
    if (slot < PAD) csrp[d * PAD + slot] = s;
  }
}

// ---------------- casts / weight packing (merged: one dispatch) ----------------

// blocks [0, CAST_BLOCKS): x f32 -> bf16.
// blocks [CAST_BLOCKS, CAST_BLOCKS+256): pack BOTH layers' W = [Wl ; Wr]
// (K=256, N=128) into B-fragment order for mfma_f32_16x16x32_bf16.
__global__ __launch_bounds__(256) void k_prep(
    const float* __restrict__ x, unsigned short* __restrict__ xb,
    const float* __restrict__ Wl1, const float* __restrict__ Wr1,
    const float* __restrict__ Wl2, const float* __restrict__ Wr2,
    unsigned short* __restrict__ Wp1, unsigned short* __restrict__ Wp2) {
  int blk = blockIdx.x;
  int tid = threadIdx.x;
  if (blk < CAST_BLOCKS) {
    int i = blk * 256 + tid;
    float4 a = *reinterpret_cast<const float4*>(x + (size_t)i * 8);
    float4 c = *reinterpret_cast<const float4*>(x + (size_t)i * 8 + 4);
    uint4 o;
    o.x = (uint32)f2bf(a.x) | ((uint32)f2bf(a.y) << 16);
    o.y = (uint32)f2bf(a.z) | ((uint32)f2bf(a.w) << 16);
    o.z = (uint32)f2bf(c.x) | ((uint32)f2bf(c.y) << 16);
    o.w = (uint32)f2bf(c.z) | ((uint32)f2bf(c.w) << 16);
    *reinterpret_cast<uint4*>(xb + (size_t)i * 8) = o;
  } else {
    int t = (blk - CAST_BLOCKS) * 256 + tid;   // 65536
    int which = t >> 15;
    int tt = t & 32767;
    int j = tt & 7;
    int lane = (tt >> 3) & 63;
    int tile = (tt >> 9) & 1;
    int ks = (tt >> 10) & 7;
    int ng = (tt >> 13) & 3;
    int k = ks * 32 + (lane >> 4) * 8 + j;
    int n = ng * 32 + tile * 16 + (lane & 15);
    const float* Wl = which ? Wl2 : Wl1;
    const float* Wr = which ? Wr2 : Wr1;
    float w = (k < 128) ? Wl[k * 128 + n] : Wr[(k - 128) * 128 + n];
    (which ? Wp2 : Wp1)[tt] = f2bf(w);
  }
}

// ---------------- mean aggregation (max MLP) ----------------
// 16 lanes per node, 8 gathers in flight per lane (~70 VGPR), 6 waves/EU.
// Counters r1: VALUBusy 29%, hbm 45%, occ 68%, nothing saturated ->
// latency-bound; deepen the pipeline.

#define ACC8(v)                                          \
  acc[0] += bflo(v.x); acc[1] += bfhi(v.x);              \
  acc[2] += bflo(v.y); acc[3] += bfhi(v.y);              \
  acc[4] += bflo(v.z); acc[5] += bfhi(v.z);              \
  acc[6] += bflo(v.w); acc[7] += bfhi(v.w);

__global__ __launch_bounds__(256, 6) void k_mean(
    const unsigned short* __restrict__ table,
    const int* __restrict__ cnt, const int* __restrict__ csrp,
    unsigned short* __restrict__ meanb) {
  int g = threadIdx.x >> 4;          // node group 0..15
  int l = threadIdx.x & 15;          // 16B lane within row
  int node = blockIdx.x * 16 + g;    // grid = NTILES -> exact cover
  int deg = cnt[node];
  if (deg > PAD) deg = PAD;
  const int* row = csrp + (size_t)node * PAD;
  float acc[8] = {0.f, 0.f, 0.f, 0.f, 0.f, 0.f, 0.f, 0.f};
  int e = 0;
  for (; e + 8 <= deg; e += 8) {     // 8 gathers in flight
    int s0 = row[e], s1 = row[e + 1], s2 = row[e + 2], s3 = row[e + 3];
    int s4 = row[e + 4], s5 = row[e + 5], s6 = row[e + 6], s7 = row[e + 7];
    uint4 v0 = *reinterpret_cast<const uint4*>(table + (size_t)s0 * D + l * 8);
    uint4 v1 = *reinterpret_cast<const uint4*>(table + (size_t)s1 * D + l * 8);
    uint4 v2 = *reinterpret_cast<const uint4*>(table + (size_t)s2 * D + l * 8);
    uint4 v3 = *reinterpret_cast<const uint4*>(table + (size_t)s3 * D + l * 8);
    uint4 v4 = *reinterpret_cast<const uint4*>(table + (size_t)s4 * D + l * 8);
    uint4 v5 = *reinterpret_cast<const uint4*>(table + (size_t)s5 * D + l * 8);
    uint4 v6 = *reinterpret_cast<const uint4*>(table + (size_t)s6 * D + l * 8);
    uint4 v7 = *reinterpret_cast<const uint4*>(table + (size_t)s7 * D + l * 8);
    ACC8(v0) ACC8(v1) ACC8(v2) ACC8(v3)
    ACC8(v4) ACC8(v5) ACC8(v6) ACC8(v7)
  }
  for (; e + 4 <= deg; e += 4) {
    int s0 = row[e], s1 = row[e + 1], s2 = row[e + 2], s3 = row[e + 3];
    uint4 v0 = *reinterpret_cast<const uint4*>(table + (size_t)s0 * D + l * 8);
    uint4 v1 = *reinterpret_cast<const uint4*>(table + (size_t)s1 * D + l * 8);
    uint4 v2 = *reinterpret_cast<const uint4*>(table + (size_t)s2 * D + l * 8);
    uint4 v3 = *reinterpret_cast<const uint4*>(table + (size_t)s3 * D + l * 8);
    ACC8(v0) ACC8(v1) ACC8(v2) ACC8(v3)
  }
  for (; e < deg; ++e) {
    int s0 = row[e];
    uint4 v0 = *reinterpret_cast<const uint4*>(table + (size_t)s0 * D + l * 8);
    ACC8(v0)
  }
  float inv = (deg > 0) ? 1.0f / (float)deg : 0.0f;
  uint4 o;
  o.x = (uint32)f2bf(acc[0] * inv) | ((uint32)f2bf(acc[1] * inv) << 16);
  o.y = (uint32)f2bf(acc[2] * inv) | ((uint32)f2bf(acc[3] * inv) << 16);
  o.z = (uint32)f2bf(acc[4] * inv) | ((uint32)f2bf(acc[5] * inv) << 16);
  o.w = (uint32)f2bf(acc[6] * inv) | ((uint32)f2bf(acc[7] * inv) << 16);
  *reinterpret_cast<uint4*>(meanb + (size_t)node * D + l * 8) = o;
}

// ---------------- dense GEMM: [mean | x] @ Wp ----------------
// Weights register-resident (Bf = 64 VGPR), A-frags straight from global rows.
// No LDS, no barriers; low occupancy is fine (streaming + MFMA-bound, tiny op).
__global__ __launch_bounds__(256) void k_gemm(
    const unsigned short* __restrict__ xrows,   // x-half rows (xb or hb)
    const unsigned short* __restrict__ mrows,   // mean rows
    const unsigned short* __restrict__ Wp, const float* __restrict__ bias,
    void* __restrict__ outp, int relu_bf16_out) {
  int tid = threadIdx.x;
  int wave = tid >> 6;
  int lane = tid & 63;
  int q = lane >> 4;
  int r = lane & 15;

  short8 Bf[8][2];
  const unsigned short* wp = Wp + ((size_t)wave * 8 * 2) * 64 * 8 + lane * 8;
#pragma unroll
  for (int ks = 0; ks < 8; ++ks)
#pragma unroll
    for (int t = 0; t < 2; ++t)
      Bf[ks][t] = *reinterpret_cast<const short8*>(wp + (ks * 2 + t) * 512);

  float bia0 = bias[wave * 32 + r];
  float bia1 = bias[wave * 32 + 16 + r];

  for (int tile = blockIdx.x; tile < NTILES; tile += GRID_GEMM) {
    int n0 = tile * 16;
    const unsigned short* am = mrows + (size_t)(n0 + r) * D + q * 8;
    const unsigned short* ax = xrows + (size_t)(n0 + r) * D + q * 8;
    short8 A[8];
#pragma unroll
    for (int ks = 0; ks < 4; ++ks)
      A[ks] = *reinterpret_cast<const short8*>(am + ks * 32);
#pragma unroll
    for (int ks = 0; ks < 4; ++ks)
      A[4 + ks] = *reinterpret_cast<const short8*>(ax + ks * 32);

    f32x4 c0 = {0.f, 0.f, 0.f, 0.f}, c1 = {0.f, 0.f, 0.f, 0.f};
#pragma unroll
    for (int ks = 0; ks < 8; ++ks) {
      c0 = __builtin_amdgcn_mfma_f32_16x16x32_bf16(A[ks], Bf[ks][0], c0, 0, 0, 0);
      c1 = __builtin_amdgcn_mfma_f32_16x16x32_bf16(A[ks], Bf[ks][1], c1, 0, 0, 0);
    }

    int orow = n0 + q * 4;   // C: col=lane&15, row=quad*4+reg
    if (relu_bf16_out) {
      unsigned short* ob = (unsigned short*)outp + (size_t)orow * D + wave * 32 + r;
#pragma unroll
      for (int gg = 0; gg < 4; ++gg) {
        ob[(size_t)gg * D] = f2bf(fmaxf(c0[gg] + bia0, 0.f));
        ob[(size_t)gg * D + 16] = f2bf(fmaxf(c1[gg] + bia1, 0.f));
      }
    } else {
      float* of = (float*)outp + (size_t)orow * D + wave * 32 + r;
#pragma unroll
      for (int gg = 0; gg < 4; ++gg) {
        of[(size_t)gg * D] = c0[gg] + bia0;
        of[(size_t)gg * D + 16] = c1[gg] + bia1;
      }
    }
  }
}

// ---------------- launch ----------------

extern "C" void kernel_launch(void* const* d_in, const int* in_sizes, int n_in,
                              void* d_out, int out_size, void* d_ws, size_t ws_size,
                              hipStream_t stream) {
  const float* x   = (const float*)d_in[0];
  const int*   ei  = (const int*)d_in[1];
  const float* Wl1 = (const float*)d_in[2];
  const float* Wr1 = (const float*)d_in[3];
  const float* b1  = (const float*)d_in[4];
  const float* Wl2 = (const float*)d_in[5];
  const float* Wr2 = (const float*)d_in[6];
  const float* b2  = (const float*)d_in[7];
  float* out = (float*)d_out;

  const int* esrc = ei;
  const int* edst = ei + N_EDGES;

  char* p = (char*)d_ws;
  auto take = [&](size_t bytes) {
    char* q = p;
    p += (bytes + 255) & ~(size_t)255;
    return q;
  };
  int* cnt    = (int*)take((size_t)N_NODES * 4);              // degree counters
  int* csrp   = (int*)take((size_t)N_NODES * PAD * 4);        // 19.2 MB padded CSR
  unsigned short* meanb = (unsigned short*)take((size_t)N_NODES * D * 2);
  unsigned short* xb  = (unsigned short*)take((size_t)N_NODES * D * 2);
  unsigned short* hb  = (unsigned short*)take((size_t)N_NODES * D * 2);
  unsigned short* Wp1 = (unsigned short*)take(256 * 128 * 2);
  unsigned short* Wp2 = (unsigned short*)take(256 * 128 * 2);

  // padded-CSR build: zero counters + one atomic scatter
  hipMemsetAsync(cnt, 0, (size_t)N_NODES * 4, stream);
  k_scat<<<GRID_SCAT, 256, 0, stream>>>(esrc, edst, cnt, csrp);

  // bf16 prep: x cast + both layers' weight packing, one dispatch
  k_prep<<<CAST_BLOCKS + 256, 256, 0, stream>>>(x, xb, Wl1, Wr1, Wl2, Wr2, Wp1, Wp2);

  // layer 1: meanb = mean(xb); hb = relu([meanb|xb] @ Wp1 + b1)  (bf16 out)
  k_mean<<<NTILES, 256, 0, stream>>>(xb, cnt, csrp, meanb);
  k_gemm<<<GRID_GEMM, 256, 0, stream>>>(xb, meanb, Wp1, b1, hb, 1);
  // layer 2: meanb = mean(hb); out = [meanb|hb] @ Wp2 + b2       (f32 out)
  k_mean<<<NTILES, 256, 0, stream>>>(hb, cnt, csrp, meanb);
  k_gemm<<<GRID_GEMM, 256, 0, stream>>>(hb, meanb, Wp2, b2, out, 0);
}

// Round 4
// 326.619 us; speedup vs baseline: 1.1667x; 1.1667x over previous
//
#include <hip/hip_runtime.h>
#include <stdint.h>

#define N_NODES 100000
#define N_EDGES 1600000
#define D 128
#define NBUCK 196          // ceil(N_NODES/512); bucket b = dst >> 9
#define BSTRIDE 9216       // fixed pairs region per bucket (mean 8163, +11 sigma)
#define PCHUNK 2048        // edges per k_part block (16KB x2 LDS -> 4 blocks/CU)
#define NTILES (N_NODES / 16)   // 6250 exact
#define GRID_GEMM 2048
#define CAST_BLOCKS (N_NODES * D / 8 / 256)   // 6250 exact

typedef unsigned int uint32;
typedef __attribute__((ext_vector_type(8))) short short8;   // 8 bf16 = 4 VGPRs
typedef __attribute__((ext_vector_type(4))) float f32x4;

__device__ __forceinline__ unsigned short f2bf(float f) {
  unsigned u = __builtin_bit_cast(unsigned, f);
  u += 0x7fffu + ((u >> 16) & 1u);          // round-to-nearest-even
  return (unsigned short)(u >> 16);
}
__device__ __forceinline__ float bflo(unsigned v) {
  return __builtin_bit_cast(float, v << 16);
}
__device__ __forceinline__ float bfhi(unsigned v) {
  return __builtin_bit_cast(float, v & 0xffff0000u);
}

// ---------------- CSR build (2 passes over edges, no global histogram) ------
// NOTE r3 lesson: do NOT replace this with a per-edge atomic scatter — random
// 4B scatter writes cost 15x write amplification (96MB for 6.4MB payload) and
// the atomic chain is latency-bound (k_scat measured 85-136us alone).

// Partition edges into NBUCK dst-buckets as (dst,src) pairs, coalesced runs.
__global__ __launch_bounds__(256) void k_part(const int* __restrict__ src,
                                              const int* __restrict__ dst,
                                              int* __restrict__ bcnt,
                                              uint2* __restrict__ pairs) {
  __shared__ uint2 buff[PCHUNK];     // 16 KB
  __shared__ uint2 sorted[PCHUNK];   // 16 KB
  __shared__ int hist[256], stmp[256], loff[256], cpos[256], base[256];
  int tid = threadIdx.x;
  int e0 = blockIdx.x * PCHUNK;
  int nv = N_EDGES - e0;
  if (nv > PCHUNK) nv = PCHUNK;

  hist[tid] = 0;
  __syncthreads();
  for (int i = tid; i < nv; i += 256) {
    int d = dst[e0 + i];
    int s = src[e0 + i];
    buff[i] = make_uint2((uint32)d, (uint32)s);
    atomicAdd(&hist[d >> 9], 1);
  }
  __syncthreads();
  int v = hist[tid];
  stmp[tid] = v;
  __syncthreads();
  for (int off = 1; off < 256; off <<= 1) {
    int t = (tid >= off) ? stmp[tid - off] : 0;
    __syncthreads();
    stmp[tid] += t;
    __syncthreads();
  }
  loff[tid] = stmp[tid] - v;
  cpos[tid] = stmp[tid] - v;
  base[tid] = (v > 0) ? atomicAdd(&bcnt[tid], v) : 0;   // reserve run in bucket region
  __syncthreads();
  for (int i = tid; i < nv; i += 256) {
    uint2 p = buff[i];
    int r = atomicAdd(&cpos[p.x >> 9], 1);
    sorted[r] = p;
  }
  __syncthreads();
  for (int i = tid; i < nv; i += 256) {
    uint2 p = sorted[i];
    int b = (int)(p.x >> 9);
    int local = base[b] + (i - loff[b]);
    if (local < BSTRIDE)                                // det. input: never trips
      pairs[(size_t)b * BSTRIDE + local] = p;
  }
}

// Per-bucket: scan 196 bucket counts locally, then LDS hist(512) -> scan ->
// write rowptr slice + scatter csr (plain src).
__global__ __launch_bounds__(512) void k_csr(const uint2* __restrict__ pairs,
                                             const int* __restrict__ bcnt,
                                             int* __restrict__ rowptr,
                                             int* __restrict__ csr) {
  __shared__ int hist[512], off[512], cur[512], scn[512];
  int b = blockIdx.x;
  int tid = threadIdx.x;

  // inclusive scan of bucket counts -> bucket base for this block
  int bv = (tid < NBUCK) ? bcnt[tid] : 0;
  scn[tid] = bv;
  __syncthreads();
  for (int o = 1; o < 512; o <<= 1) {
    int t = (tid >= o) ? scn[tid - o] : 0;
    __syncthreads();
    scn[tid] += t;
    __syncthreads();
  }
  int bb = (b == 0) ? 0 : scn[b - 1];
  if (b == NBUCK - 1 && tid == 0) rowptr[N_NODES] = scn[NBUCK - 1];

  int lo = b << 9;
  int hi = lo + 512;
  if (hi > N_NODES) hi = N_NODES;
  int ne = bcnt[b];
  if (ne > BSTRIDE) ne = BSTRIDE;
  const uint2* pb = pairs + (size_t)b * BSTRIDE;

  hist[tid] = 0;
  __syncthreads();
  for (int i = tid; i < ne; i += 512) atomicAdd(&hist[(int)pb[i].x - lo], 1);
  __syncthreads();
  int v = hist[tid];
  off[tid] = v;
  __syncthreads();
  for (int o = 1; o < 512; o <<= 1) {
    int t = (tid >= o) ? off[tid - o] : 0;
    __syncthreads();
    off[tid] += t;
    __syncthreads();
  }
  off[tid] -= v;               // exclusive
  cur[tid] = off[tid];
  if (lo + tid < hi) rowptr[lo + tid] = bb + off[tid];
  __syncthreads();
  for (int i = tid; i < ne; i += 512) {
    int d = (int)pb[i].x - lo;
    int slot = atomicAdd(&cur[d], 1);
    csr[bb + slot] = (int)pb[i].y;
  }
}

// ---------------- casts / weight packing (merged: one dispatch) ----------------

// blocks [0, CAST_BLOCKS): x f32 -> bf16.
// blocks [CAST_BLOCKS, CAST_BLOCKS+256): pack BOTH layers' W = [Wl ; Wr]
// (K=256, N=128) into B-fragment order for mfma_f32_16x16x32_bf16.
__global__ __launch_bounds__(256) void k_prep(
    const float* __restrict__ x, unsigned short* __restrict__ xb,
    const float* __restrict__ Wl1, const float* __restrict__ Wr1,
    const float* __restrict__ Wl2, const float* __restrict__ Wr2,
    unsigned short* __restrict__ Wp1, unsigned short* __restrict__ Wp2) {
  int blk = blockIdx.x;
  int tid = threadIdx.x;
  if (blk < CAST_BLOCKS) {
    int i = blk * 256 + tid;
    float4 a = *reinterpret_cast<const float4*>(x + (size_t)i * 8);
    float4 c = *reinterpret_cast<const float4*>(x + (size_t)i * 8 + 4);
    uint4 o;
    o.x = (uint32)f2bf(a.x) | ((uint32)f2bf(a.y) << 16);
    o.y = (uint32)f2bf(a.z) | ((uint32)f2bf(a.w) << 16);
    o.z = (uint32)f2bf(c.x) | ((uint32)f2bf(c.y) << 16);
    o.w = (uint32)f2bf(c.z) | ((uint32)f2bf(c.w) << 16);
    *reinterpret_cast<uint4*>(xb + (size_t)i * 8) = o;
  } else {
    int t = (blk - CAST_BLOCKS) * 256 + tid;   // 65536
    int which = t >> 15;
    int tt = t & 32767;
    int j = tt & 7;
    int lane = (tt >> 3) & 63;
    int tile = (tt >> 9) & 1;
    int ks = (tt >> 10) & 7;
    int ng = (tt >> 13) & 3;
    int k = ks * 32 + (lane >> 4) * 8 + j;
    int n = ng * 32 + tile * 16 + (lane & 15);
    const float* Wl = which ? Wl2 : Wl1;
    const float* Wr = which ? Wr2 : Wr1;
    float w = (k < 128) ? Wl[k * 128 + n] : Wr[(k - 128) * 128 + n];
    (which ? Wp2 : Wp1)[tt] = f2bf(w);
  }
}

// ---------------- mean aggregation (max MLP) ----------------
// 16 lanes per node, 8 gathers in flight per lane, 6 waves/EU.
// r2 counters: VALUBusy 29%, hbm 45%, occ 68%, VGPR 24, nothing saturated ->
// latency-bound; this round's single change: 4-deep -> 8-deep pipeline.

#define ACC8(v)                                          \
  acc[0] += bflo(v.x); acc[1] += bfhi(v.x);              \
  acc[2] += bflo(v.y); acc[3] += bfhi(v.y);              \
  acc[4] += bflo(v.z); acc[5] += bfhi(v.z);              \
  acc[6] += bflo(v.w); acc[7] += bfhi(v.w);

__global__ __launch_bounds__(256, 6) void k_mean(
    const unsigned short* __restrict__ table,
    const int* __restrict__ rowptr, const int* __restrict__ csr,
    unsigned short* __restrict__ meanb) {
  int g = threadIdx.x >> 4;          // node group 0..15
  int l = threadIdx.x & 15;          // 16B lane within row
  int node = blockIdx.x * 16 + g;    // grid = NTILES -> exact cover
  int beg = rowptr[node], end = rowptr[node + 1];
  float acc[8] = {0.f, 0.f, 0.f, 0.f, 0.f, 0.f, 0.f, 0.f};
  int e = beg;
  for (; e + 8 <= end; e += 8) {     // 8 gathers in flight
    int s0 = csr[e], s1 = csr[e + 1], s2 = csr[e + 2], s3 = csr[e + 3];
    int s4 = csr[e + 4], s5 = csr[e + 5], s6 = csr[e + 6], s7 = csr[e + 7];
    uint4 v0 = *reinterpret_cast<const uint4*>(table + (size_t)s0 * D + l * 8);
    uint4 v1 = *reinterpret_cast<const uint4*>(table + (size_t)s1 * D + l * 8);
    uint4 v2 = *reinterpret_cast<const uint4*>(table + (size_t)s2 * D + l * 8);
    uint4 v3 = *reinterpret_cast<const uint4*>(table + (size_t)s3 * D + l * 8);
    uint4 v4 = *reinterpret_cast<const uint4*>(table + (size_t)s4 * D + l * 8);
    uint4 v5 = *reinterpret_cast<const uint4*>(table + (size_t)s5 * D + l * 8);
    uint4 v6 = *reinterpret_cast<const uint4*>(table + (size_t)s6 * D + l * 8);
    uint4 v7 = *reinterpret_cast<const uint4*>(table + (size_t)s7 * D + l * 8);
    ACC8(v0) ACC8(v1) ACC8(v2) ACC8(v3)
    ACC8(v4) ACC8(v5) ACC8(v6) ACC8(v7)
  }
  for (; e + 4 <= end; e += 4) {
    int s0 = csr[e], s1 = csr[e + 1], s2 = csr[e + 2], s3 = csr[e + 3];
    uint4 v0 = *reinterpret_cast<const uint4*>(table + (size_t)s0 * D + l * 8);
    uint4 v1 = *reinterpret_cast<const uint4*>(table + (size_t)s1 * D + l * 8);
    uint4 v2 = *reinterpret_cast<const uint4*>(table + (size_t)s2 * D + l * 8);
    uint4 v3 = *reinterpret_cast<const uint4*>(table + (size_t)s3 * D + l * 8);
    ACC8(v0) ACC8(v1) ACC8(v2) ACC8(v3)
  }
  for (; e < end; ++e) {
    int s0 = csr[e];
    uint4 v0 = *reinterpret_cast<const uint4*>(table + (size_t)s0 * D + l * 8);
    ACC8(v0)
  }
  float inv = (end > beg) ? 1.0f / (float)(end - beg) : 0.0f;
  uint4 o;
  o.x = (uint32)f2bf(acc[0] * inv) | ((uint32)f2bf(acc[1] * inv) << 16);
  o.y = (uint32)f2bf(acc[2] * inv) | ((uint32)f2bf(acc[3] * inv) << 16);
  o.z = (uint32)f2bf(acc[4] * inv) | ((uint32)f2bf(acc[5] * inv) << 16);
  o.w = (uint32)f2bf(acc[6] * inv) | ((uint32)f2bf(acc[7] * inv) << 16);
  *reinterpret_cast<uint4*>(meanb + (size_t)node * D + l * 8) = o;
}

// ---------------- dense GEMM: [mean | x] @ Wp ----------------
// Weights register-resident (Bf = 64 VGPR), A-frags straight from global rows.
// No LDS, no barriers; low occupancy is fine (streaming + MFMA-bound, tiny op).
__global__ __launch_bounds__(256) void k_gemm(
    const unsigned short* __restrict__ xrows,   // x-half rows (xb or hb)
    const unsigned short* __restrict__ mrows,   // mean rows
    const unsigned short* __restrict__ Wp, const float* __restrict__ bias,
    void* __restrict__ outp, int relu_bf16_out) {
  int tid = threadIdx.x;
  int wave = tid >> 6;
  int lane = tid & 63;
  int q = lane >> 4;
  int r = lane & 15;

  short8 Bf[8][2];
  const unsigned short* wp = Wp + ((size_t)wave * 8 * 2) * 64 * 8 + lane * 8;
#pragma unroll
  for (int ks = 0; ks < 8; ++ks)
#pragma unroll
    for (int t = 0; t < 2; ++t)
      Bf[ks][t] = *reinterpret_cast<const short8*>(wp + (ks * 2 + t) * 512);

  float bia0 = bias[wave * 32 + r];
  float bia1 = bias[wave * 32 + 16 + r];

  for (int tile = blockIdx.x; tile < NTILES; tile += GRID_GEMM) {
    int n0 = tile * 16;
    const unsigned short* am = mrows + (size_t)(n0 + r) * D + q * 8;
    const unsigned short* ax = xrows + (size_t)(n0 + r) * D + q * 8;
    short8 A[8];
#pragma unroll
    for (int ks = 0; ks < 4; ++ks)
      A[ks] = *reinterpret_cast<const short8*>(am + ks * 32);
#pragma unroll
    for (int ks = 0; ks < 4; ++ks)
      A[4 + ks] = *reinterpret_cast<const short8*>(ax + ks * 32);

    f32x4 c0 = {0.f, 0.f, 0.f, 0.f}, c1 = {0.f, 0.f, 0.f, 0.f};
#pragma unroll
    for (int ks = 0; ks < 8; ++ks) {
      c0 = __builtin_amdgcn_mfma_f32_16x16x32_bf16(A[ks], Bf[ks][0], c0, 0, 0, 0);
      c1 = __builtin_amdgcn_mfma_f32_16x16x32_bf16(A[ks], Bf[ks][1], c1, 0, 0, 0);
    }

    int orow = n0 + q * 4;   // C: col=lane&15, row=quad*4+reg
    if (relu_bf16_out) {
      unsigned short* ob = (unsigned short*)outp + (size_t)orow * D + wave * 32 + r;
#pragma unroll
      for (int gg = 0; gg < 4; ++gg) {
        ob[(size_t)gg * D] = f2bf(fmaxf(c0[gg] + bia0, 0.f));
        ob[(size_t)gg * D + 16] = f2bf(fmaxf(c1[gg] + bia1, 0.f));
      }
    } else {
      float* of = (float*)outp + (size_t)orow * D + wave * 32 + r;
#pragma unroll
      for (int gg = 0; gg < 4; ++gg) {
        of[(size_t)gg * D] = c0[gg] + bia0;
        of[(size_t)gg * D + 16] = c1[gg] + bia1;
      }
    }
  }
}

// ---------------- launch ----------------

extern "C" void kernel_launch(void* const* d_in, const int* in_sizes, int n_in,
                              void* d_out, int out_size, void* d_ws, size_t ws_size,
                              hipStream_t stream) {
  const float* x   = (const float*)d_in[0];
  const int*   ei  = (const int*)d_in[1];
  const float* Wl1 = (const float*)d_in[2];
  const float* Wr1 = (const float*)d_in[3];
  const float* b1  = (const float*)d_in[4];
  const float* Wl2 = (const float*)d_in[5];
  const float* Wr2 = (const float*)d_in[6];
  const float* b2  = (const float*)d_in[7];
  float* out = (float*)d_out;

  const int* esrc = ei;
  const int* edst = ei + N_EDGES;

  char* p = (char*)d_ws;
  auto take = [&](size_t bytes) {
    char* q = p;
    p += (bytes + 255) & ~(size_t)255;
    return q;
  };
  int* bcnt   = (int*)take(256 * 4);
  int* rowptr = (int*)take((size_t)(N_NODES + 1) * 4);
  int* csr    = (int*)take((size_t)N_EDGES * 4);
  // pairs is dead after k_csr; meanb (written by k_mean, later) aliases it.
  size_t pairs_bytes = (size_t)NBUCK * BSTRIDE * 8;          // 14.5 MB
  size_t meanb_bytes = (size_t)N_NODES * D * 2;              // 25.6 MB
  char* unionbuf = (char*)take(pairs_bytes > meanb_bytes ? pairs_bytes : meanb_bytes);
  uint2* pairs = (uint2*)unionbuf;
  unsigned short* meanb = (unsigned short*)unionbuf;
  unsigned short* xb  = (unsigned short*)take((size_t)N_NODES * D * 2);
  unsigned short* hb  = (unsigned short*)take((size_t)N_NODES * D * 2);
  unsigned short* Wp1 = (unsigned short*)take(256 * 128 * 2);
  unsigned short* Wp2 = (unsigned short*)take(256 * 128 * 2);

  const int npart = (N_EDGES + PCHUNK - 1) / PCHUNK;   // 782

  // CSR build: partition -> per-bucket (scan + rowptr + csr)
  hipMemsetAsync(bcnt, 0, 256 * 4, stream);
  k_part<<<npart, 256, 0, stream>>>(esrc, edst, bcnt, pairs);
  k_csr<<<NBUCK, 512, 0, stream>>>(pairs, bcnt, rowptr, csr);

  // bf16 prep: x cast + both layers' weight packing, one dispatch
  k_prep<<<CAST_BLOCKS + 256, 256, 0, stream>>>(x, xb, Wl1, Wr1, Wl2, Wr2, Wp1, Wp2);

  // layer 1: meanb = mean(xb); hb = relu([meanb|xb] @ Wp1 + b1)  (bf16 out)
  k_mean<<<NTILES, 256, 0, stream>>>(xb, rowptr, csr, meanb);
  k_gemm<<<GRID_GEMM, 256, 0, stream>>>(xb, meanb, Wp1, b1, hb, 1);
  // layer 2: meanb = mean(hb); out = [meanb|hb] @ Wp2 + b2       (f32 out)
  k_mean<<<NTILES, 256, 0, stream>>>(hb, rowptr, csr, meanb);
  k_gemm<<<GRID_GEMM, 256, 0, stream>>>(hb, meanb, Wp2, b2, out, 0);
}

// Round 6
// 318.967 us; speedup vs baseline: 1.1947x; 1.0240x over previous
//
#include <hip/hip_runtime.h>
#include <stdint.h>

#define N_NODES 100000
#define N_EDGES 1600000
#define D 128
#define NBUCK 196          // ceil(N_NODES/512); bucket b = dst >> 9
#define BSTRIDE 9216       // fixed pairs region per bucket (mean 8163, +11 sigma)
#define PCHUNK 2048        // edges per k_part block (16KB x2 LDS -> 4 blocks/CU)
#define NTILE32 (N_NODES / 32)   // 3125 exact (32-node tiles for fused kernel)
#define CASTB 3125         // 512-thread cast blocks: 3125*512*8 = 12.8M floats exact
#define WPACKB 128         // 128*512 = 65536 weight elements (both layers)

typedef unsigned int uint32;
typedef __attribute__((ext_vector_type(8))) short short8;   // 8 bf16 = 4 VGPRs
typedef __attribute__((ext_vector_type(4))) float f32x4;

__device__ __forceinline__ unsigned short f2bf(float f) {
  unsigned u = __builtin_bit_cast(unsigned, f);
  u += 0x7fffu + ((u >> 16) & 1u);          // round-to-nearest-even
  return (unsigned short)(u >> 16);
}
__device__ __forceinline__ float bflo(unsigned v) {
  return __builtin_bit_cast(float, v << 16);
}
__device__ __forceinline__ float bfhi(unsigned v) {
  return __builtin_bit_cast(float, v & 0xffff0000u);
}

// ---------------- CSR build (2 passes over edges, no global histogram) ------
// r3 lesson: do NOT replace with per-edge atomic scatter — random 4B scatter
// writes cost 15x write amplification (96MB for 6.4MB payload); k_scat
// measured 85-136us alone. Coalesced bucket runs are the point of this build.

__global__ __launch_bounds__(256) void k_part(const int* __restrict__ src,
                                              const int* __restrict__ dst,
                                              int* __restrict__ bcnt,
                                              uint2* __restrict__ pairs) {
  __shared__ uint2 buff[PCHUNK];     // 16 KB
  __shared__ uint2 sorted[PCHUNK];   // 16 KB
  __shared__ int hist[256], stmp[256], loff[256], cpos[256], base[256];
  int tid = threadIdx.x;
  int e0 = blockIdx.x * PCHUNK;
  int nv = N_EDGES - e0;
  if (nv > PCHUNK) nv = PCHUNK;

  hist[tid] = 0;
  __syncthreads();
  for (int i = tid; i < nv; i += 256) {
    int d = dst[e0 + i];
    int s = src[e0 + i];
    buff[i] = make_uint2((uint32)d, (uint32)s);
    atomicAdd(&hist[d >> 9], 1);
  }
  __syncthreads();
  int v = hist[tid];
  stmp[tid] = v;
  __syncthreads();
  for (int off = 1; off < 256; off <<= 1) {
    int t = (tid >= off) ? stmp[tid - off] : 0;
    __syncthreads();
    stmp[tid] += t;
    __syncthreads();
  }
  loff[tid] = stmp[tid] - v;
  cpos[tid] = stmp[tid] - v;
  base[tid] = (v > 0) ? atomicAdd(&bcnt[tid], v) : 0;   // reserve run in bucket region
  __syncthreads();
  for (int i = tid; i < nv; i += 256) {
    uint2 p = buff[i];
    int r = atomicAdd(&cpos[p.x >> 9], 1);
    sorted[r] = p;
  }
  __syncthreads();
  for (int i = tid; i < nv; i += 256) {
    uint2 p = sorted[i];
    int b = (int)(p.x >> 9);
    int local = base[b] + (i - loff[b]);
    if (local < BSTRIDE)                                // det. input: never trips
      pairs[(size_t)b * BSTRIDE + local] = p;
  }
}

// Merged dispatch: blocks [0,NBUCK) build per-bucket rowptr+csr; the
// remaining 3253 blocks (independent prep work: x cast + weight packing)
// fill the ~3/4 of the GPU that the 196 csr blocks leave idle.
__global__ __launch_bounds__(512) void k_csr_prep(
    const uint2* __restrict__ pairs, const int* __restrict__ bcnt,
    int* __restrict__ rowptr, int* __restrict__ csr,
    const float* __restrict__ x, unsigned short* __restrict__ xb,
    const float* __restrict__ Wl1, const float* __restrict__ Wr1,
    const float* __restrict__ Wl2, const float* __restrict__ Wr2,
    unsigned short* __restrict__ Wp1, unsigned short* __restrict__ Wp2) {
  __shared__ int hist[512], off[512], cur[512], scn[512];
  int tid = threadIdx.x;
  int blk = blockIdx.x;

  if (blk >= NBUCK) {
    int pb = blk - NBUCK;
    if (pb < CASTB) {                     // x f32 -> bf16, 8 elems/thread
      size_t i = (size_t)pb * 512 + tid;  // < 1.6M exact
      float4 a = *reinterpret_cast<const float4*>(x + i * 8);
      float4 c = *reinterpret_cast<const float4*>(x + i * 8 + 4);
      uint4 o;
      o.x = (uint32)f2bf(a.x) | ((uint32)f2bf(a.y) << 16);
      o.y = (uint32)f2bf(a.z) | ((uint32)f2bf(a.w) << 16);
      o.z = (uint32)f2bf(c.x) | ((uint32)f2bf(c.y) << 16);
      o.w = (uint32)f2bf(c.z) | ((uint32)f2bf(c.w) << 16);
      *reinterpret_cast<uint4*>(xb + i * 8) = o;
    } else {                              // pack both layers' W into B-frag order
      int t = (pb - CASTB) * 512 + tid;   // < 65536 exact
      int which = t >> 15;
      int tt = t & 32767;
      int j = tt & 7;
      int lane = (tt >> 3) & 63;
      int tile = (tt >> 9) & 1;
      int ks = (tt >> 10) & 7;
      int ng = (tt >> 13) & 3;
      int k = ks * 32 + (lane >> 4) * 8 + j;
      int n = ng * 32 + tile * 16 + (lane & 15);
      const float* Wl = which ? Wl2 : Wl1;
      const float* Wr = which ? Wr2 : Wr1;
      float w = (k < 128) ? Wl[k * 128 + n] : Wr[(k - 128) * 128 + n];
      (which ? Wp2 : Wp1)[tt] = f2bf(w);
    }
    return;
  }

  int b = blk;
  // inclusive scan of bucket counts -> bucket base for this block
  int bv = (tid < NBUCK) ? bcnt[tid] : 0;
  scn[tid] = bv;
  __syncthreads();
  for (int o = 1; o < 512; o <<= 1) {
    int t = (tid >= o) ? scn[tid - o] : 0;
    __syncthreads();
    scn[tid] += t;
    __syncthreads();
  }
  int bb = (b == 0) ? 0 : scn[b - 1];
  if (b == NBUCK - 1 && tid == 0) rowptr[N_NODES] = scn[NBUCK - 1];

  int lo = b << 9;
  int hi = lo + 512;
  if (hi > N_NODES) hi = N_NODES;
  int ne = bcnt[b];
  if (ne > BSTRIDE) ne = BSTRIDE;
  const uint2* pb2 = pairs + (size_t)b * BSTRIDE;

  hist[tid] = 0;
  __syncthreads();
  for (int i = tid; i < ne; i += 512) atomicAdd(&hist[(int)pb2[i].x - lo], 1);
  __syncthreads();
  int v = hist[tid];
  off[tid] = v;
  __syncthreads();
  for (int o = 1; o < 512; o <<= 1) {
    int t = (tid >= o) ? off[tid - o] : 0;
    __syncthreads();
    off[tid] += t;
    __syncthreads();
  }
  off[tid] -= v;               // exclusive
  cur[tid] = off[tid];
  if (lo + tid < hi) rowptr[lo + tid] = bb + off[tid];
  __syncthreads();
  for (int i = tid; i < ne; i += 512) {
    int d = (int)pb2[i].x - lo;
    int slot = atomicAdd(&cur[d], 1);
    csr[bb + slot] = (int)pb2[i].y;
  }
}

// ---------------- fused mean-aggregate + GEMM (per 32-node tile) ----------
// Phase 1 = exact r4 k_mean gather (proven throughput-saturated; untouched).
// Phase 2 loads weights into registers ONLY after the barrier, so gather-phase
// occupancy is preserved (r0 lesson: weight-resident-through-gather = 28% occ).
// mean crosses phases via 8 KB LDS (XOR-swizzled 16B groups, bank-spread).

#define ACC8(v)                                          \
  acc[0] += bflo(v.x); acc[1] += bfhi(v.x);              \
  acc[2] += bflo(v.y); acc[3] += bfhi(v.y);              \
  acc[4] += bflo(v.z); acc[5] += bfhi(v.z);              \
  acc[6] += bflo(v.w); acc[7] += bfhi(v.w);

__global__ __launch_bounds__(512, 4) void k_fused(
    const unsigned short* __restrict__ table,   // gather table AND x-half rows
    const int* __restrict__ rowptr, const int* __restrict__ csr,
    const unsigned short* __restrict__ Wp, const float* __restrict__ bias,
    void* __restrict__ outp, int relu_bf16_out) {
  __shared__ unsigned short meanB[32 * 128];   // 8 KB, swizzled 16B groups
  int tid = threadIdx.x;
  int g = tid >> 4;          // node 0..31 within tile
  int l = tid & 15;          // 16B lane within row
  int tile = blockIdx.x;     // grid = NTILE32 exact
  int node = tile * 32 + g;

  // ---- phase 1: mean of in-neighbors (identical to r4 k_mean) ----
  int beg = rowptr[node], end = rowptr[node + 1];
  float acc[8] = {0.f, 0.f, 0.f, 0.f, 0.f, 0.f, 0.f, 0.f};
  int e = beg;
  for (; e + 8 <= end; e += 8) {     // 8 gathers in flight
    int s0 = csr[e], s1 = csr[e + 1], s2 = csr[e + 2], s3 = csr[e + 3];
    int s4 = csr[e + 4], s5 = csr[e + 5], s6 = csr[e + 6], s7 = csr[e + 7];
    uint4 v0 = *reinterpret_cast<const uint4*>(table + (size_t)s0 * D + l * 8);
    uint4 v1 = *reinterpret_cast<const uint4*>(table + (size_t)s1 * D + l * 8);
    uint4 v2 = *reinterpret_cast<const uint4*>(table + (size_t)s2 * D + l * 8);
    uint4 v3 = *reinterpret_cast<const uint4*>(table + (size_t)s3 * D + l * 8);
    uint4 v4 = *reinterpret_cast<const uint4*>(table + (size_t)s4 * D + l * 8);
    uint4 v5 = *reinterpret_cast<const uint4*>(table + (size_t)s5 * D + l * 8);
    uint4 v6 = *reinterpret_cast<const uint4*>(table + (size_t)s6 * D + l * 8);
    uint4 v7 = *reinterpret_cast<const uint4*>(table + (size_t)s7 * D + l * 8);
    ACC8(v0) ACC8(v1) ACC8(v2) ACC8(v3)
    ACC8(v4) ACC8(v5) ACC8(v6) ACC8(v7)
  }
  for (; e + 4 <= end; e += 4) {
    int s0 = csr[e], s1 = csr[e + 1], s2 = csr[e + 2], s3 = csr[e + 3];
    uint4 v0 = *reinterpret_cast<const uint4*>(table + (size_t)s0 * D + l * 8);
    uint4 v1 = *reinterpret_cast<const uint4*>(table + (size_t)s1 * D + l * 8);
    uint4 v2 = *reinterpret_cast<const uint4*>(table + (size_t)s2 * D + l * 8);
    uint4 v3 = *reinterpret_cast<const uint4*>(table + (size_t)s3 * D + l * 8);
    ACC8(v0) ACC8(v1) ACC8(v2) ACC8(v3)
  }
  for (; e < end; ++e) {
    int s0 = csr[e];
    uint4 v0 = *reinterpret_cast<const uint4*>(table + (size_t)s0 * D + l * 8);
    ACC8(v0)
  }
  float inv = (end > beg) ? 1.0f / (float)(end - beg) : 0.0f;
  uint4 o;
  o.x = (uint32)f2bf(acc[0] * inv) | ((uint32)f2bf(acc[1] * inv) << 16);
  o.y = (uint32)f2bf(acc[2] * inv) | ((uint32)f2bf(acc[3] * inv) << 16);
  o.z = (uint32)f2bf(acc[4] * inv) | ((uint32)f2bf(acc[5] * inv) << 16);
  o.w = (uint32)f2bf(acc[6] * inv) | ((uint32)f2bf(acc[7] * inv) << 16);
  // swizzled store: content-group l -> slot l^(g&15)  (bank-spread reads)
  *reinterpret_cast<uint4*>(&meanB[g * 128 + (l ^ (g & 15)) * 8]) = o;
  __syncthreads();

  // ---- phase 2: [mean | x] @ Wp for this tile ----
  int wave = tid >> 6;       // 8 waves: wr = row-half, wc = col-quarter
  int lane = tid & 63;
  int wr = wave >> 2;
  int wc = wave & 3;
  int q = lane >> 4;
  int r = lane & 15;

  short8 Bf[8][2];           // registers live only in phase 2
  const unsigned short* wp = Wp + (size_t)wc * 8192 + lane * 8;
#pragma unroll
  for (int ks = 0; ks < 8; ++ks)
#pragma unroll
    for (int t = 0; t < 2; ++t)
      Bf[ks][t] = *reinterpret_cast<const short8*>(wp + (ks * 2 + t) * 512);

  int arow = wr * 16 + r;    // A row within tile
  short8 A[8];
  const unsigned short* ax = table + (size_t)(tile * 32 + arow) * D + q * 8;
#pragma unroll
  for (int ks = 0; ks < 4; ++ks)
    A[4 + ks] = *reinterpret_cast<const short8*>(ax + ks * 32);
#pragma unroll
  for (int ks = 0; ks < 4; ++ks) {   // mean half: slot = group ^ (row&15)
    int slot = (ks * 4 + q) ^ r;
    A[ks] = *reinterpret_cast<const short8*>(&meanB[arow * 128 + slot * 8]);
  }

  f32x4 c0 = {0.f, 0.f, 0.f, 0.f}, c1 = {0.f, 0.f, 0.f, 0.f};
#pragma unroll
  for (int ks = 0; ks < 8; ++ks) {
    c0 = __builtin_amdgcn_mfma_f32_16x16x32_bf16(A[ks], Bf[ks][0], c0, 0, 0, 0);
    c1 = __builtin_amdgcn_mfma_f32_16x16x32_bf16(A[ks], Bf[ks][1], c1, 0, 0, 0);
  }

  float bia0 = bias[wc * 32 + r];
  float bia1 = bias[wc * 32 + 16 + r];
  int orow = tile * 32 + wr * 16 + q * 4;   // C: col=lane&15, row=quad*4+reg
  if (relu_bf16_out) {
    unsigned short* ob = (unsigned short*)outp + (size_t)orow * D + wc * 32 + r;
#pragma unroll
    for (int gg = 0; gg < 4; ++gg) {
      ob[(size_t)gg * D] = f2bf(fmaxf(c0[gg] + bia0, 0.f));
      ob[(size_t)gg * D + 16] = f2bf(fmaxf(c1[gg] + bia1, 0.f));
    }
  } else {
    float* of = (float*)outp + (size_t)orow * D + wc * 32 + r;
#pragma unroll
    for (int gg = 0; gg < 4; ++gg) {
      of[(size_t)gg * D] = c0[gg] + bia0;
      of[(size_t)gg * D + 16] = c1[gg] + bia1;
    }
  }
}

// ---------------- launch ----------------

extern "C" void kernel_launch(void* const* d_in, const int* in_sizes, int n_in,
                              void* d_out, int out_size, void* d_ws, size_t ws_size,
                              hipStream_t stream) {
  const float* x   = (const float*)d_in[0];
  const int*   ei  = (const int*)d_in[1];
  const float* Wl1 = (const float*)d_in[2];
  const float* Wr1 = (const float*)d_in[3];
  const float* b1  = (const float*)d_in[4];
  const float* Wl2 = (const float*)d_in[5];
  const float* Wr2 = (const float*)d_in[6];
  const float* b2  = (const float*)d_in[7];
  float* out = (float*)d_out;

  const int* esrc = ei;
  const int* edst = ei + N_EDGES;

  char* p = (char*)d_ws;
  auto take = [&](size_t bytes) {
    char* q = p;
    p += (bytes + 255) & ~(size_t)255;
    return q;
  };
  int* bcnt   = (int*)take(256 * 4);
  int* rowptr = (int*)take((size_t)(N_NODES + 1) * 4);
  int* csr    = (int*)take((size_t)N_EDGES * 4);
  uint2* pairs = (uint2*)take((size_t)NBUCK * BSTRIDE * 8);   // 14.5 MB
  unsigned short* xb  = (unsigned short*)take((size_t)N_NODES * D * 2);
  unsigned short* hb  = (unsigned short*)take((size_t)N_NODES * D * 2);
  unsigned short* Wp1 = (unsigned short*)take(256 * 128 * 2);
  unsigned short* Wp2 = (unsigned short*)take(256 * 128 * 2);

  const int npart = (N_EDGES + PCHUNK - 1) / PCHUNK;   // 782

  // CSR build: partition -> (per-bucket rowptr+csr || prep on idle CUs)
  hipMemsetAsync(bcnt, 0, 256 * 4, stream);
  k_part<<<npart, 256, 0, stream>>>(esrc, edst, bcnt, pairs);
  k_csr_prep<<<NBUCK + CASTB + WPACKB, 512, 0, stream>>>(
      pairs, bcnt, rowptr, csr, x, xb, Wl1, Wr1, Wl2, Wr2, Wp1, Wp2);

  // layer 1: hb = relu([mean(xb)|xb] @ Wp1 + b1)   (bf16 out)
  k_fused<<<NTILE32, 512, 0, stream>>>(xb, rowptr, csr, Wp1, b1, hb, 1);
  // layer 2: out = [mean(hb)|hb] @ Wp2 + b2        (f32 out)
  k_fused<<<NTILE32, 512, 0, stream>>>(hb, rowptr, csr, Wp2, b2, out, 0);
}